// Round 12
// baseline (158.313 us; speedup 1.0000x reference)
//
#include <hip/hip_runtime.h>

#define BATCH 4096
#define T 256
#define IN 64
#define CELL 128
#define ZDIM 256
#define OUTD 64
#define M 16   // batch rows per block (one MFMA row-tile)

using f32x4 = __attribute__((ext_vector_type(4))) float;
using f4    = __attribute__((ext_vector_type(4))) float;
using h16x8 = __attribute__((ext_vector_type(8))) _Float16;
using fp16x2 = __attribute__((ext_vector_type(2))) __fp16;   // cvt_pkrtz result type
typedef unsigned int u32t;

union h8cast { h16x8 v; fp16x2 h[4]; };
union pkcast { fp16x2 h; u32t u; };

#define MFMA16(A, B, C) __builtin_amdgcn_mfma_f32_16x16x32_f16(A, B, C, 0, 0, 0)

// gate for cell pair (colA=32w+2q, colB=colA+1) at row 4g+I.
// Weights/biases pre-scaled: f-cols by -log2e, g-cols by 2*log2e, so
// sigmoid(zf) = rcp(1+exp2(zf')) and tanh(zg) = 1-2*rcp(exp2(zg')+1).
#define GATEPK(I)                                                               \
  {                                                                             \
    float fgA = __builtin_amdgcn_rcpf(1.f + __builtin_amdgcn_exp2f(fa[I]));     \
    float thA = 1.f - 2.f * __builtin_amdgcn_rcpf(__builtin_amdgcn_exp2f(ga[I]) + 1.f); \
    float cnA = fgA * (cregA[I] - thA) + thA;                                   \
    float fgB = __builtin_amdgcn_rcpf(1.f + __builtin_amdgcn_exp2f(fb[I]));     \
    float thB = 1.f - 2.f * __builtin_amdgcn_rcpf(__builtin_amdgcn_exp2f(gb[I]) + 1.f); \
    float cnB = fgB * (cregB[I] - thB) + thB;                                   \
    cregA[I] = cnA; cregB[I] = cnB;                                             \
    pkcast pk_; pk_.h = __builtin_amdgcn_cvt_pkrtz(cnA, cnB);                   \
    *(u32t*)(cn_ + woPk[I]) = pk_.u;                                            \
  }

#define CVT8(D0, D1, S0, S1, S2, S3)                                            \
  {                                                                             \
    h8cast u0_, u1_;                                                            \
    u0_.h[0] = __builtin_amdgcn_cvt_pkrtz(S0[0], S0[1]);                        \
    u0_.h[1] = __builtin_amdgcn_cvt_pkrtz(S0[2], S0[3]);                        \
    u0_.h[2] = __builtin_amdgcn_cvt_pkrtz(S1[0], S1[1]);                        \
    u0_.h[3] = __builtin_amdgcn_cvt_pkrtz(S1[2], S1[3]);                        \
    u1_.h[0] = __builtin_amdgcn_cvt_pkrtz(S2[0], S2[1]);                        \
    u1_.h[1] = __builtin_amdgcn_cvt_pkrtz(S2[2], S2[3]);                        \
    u1_.h[2] = __builtin_amdgcn_cvt_pkrtz(S3[0], S3[1]);                        \
    u1_.h[3] = __builtin_amdgcn_cvt_pkrtz(S3[2], S3[3]);                        \
    D0 = u0_.v; D1 = u1_.v;                                                     \
  }

// One step at time TT. c(TT) is in cbuf[P]. Loop-carried: l1* = chain link 1
// of step TT (computed LAST step, pre-barrier, from own fragment), zx*CUR =
// seed consumed by that link, zx*NXT produced here for step TT+1.
// Fragment rotation: link j uses k-fragment (w+j)&3; fragment w (own) is
// written by this wave's gates -> readable pre-barrier (in-order LDS).
#define STEP(CUR, NXT, TT, P)                                                   \
  {                                                                             \
    /* post-barrier: other waves' fragments of c(TT) */                         \
    const char* cb_ = cbuf[P];                                                  \
    h16x8 ca1 = *(const h16x8*)(cb_ + ro1);                                     \
    h16x8 ca2 = *(const h16x8*)(cb_ + ro2);                                     \
    h16x8 ca3 = *(const h16x8*)(cb_ + ro3);                                     \
    /* zx(TT+1): independent MFMAs issue during ds_read latency */              \
    zxf##NXT##A = MFMA16(xa_##NXT##0, bA0, bqA);                                \
    zxf##NXT##B = MFMA16(xa_##NXT##0, bB0, bqB);                                \
    zxg##NXT##A = MFMA16(xa_##NXT##0, bC0, bqC);                                \
    zxg##NXT##B = MFMA16(xa_##NXT##0, bD0, bqD);                                \
    zxf##NXT##A = MFMA16(xa_##NXT##1, bA1, zxf##NXT##A);                        \
    zxf##NXT##B = MFMA16(xa_##NXT##1, bB1, zxf##NXT##B);                        \
    zxg##NXT##A = MFMA16(xa_##NXT##1, bC1, zxg##NXT##A);                        \
    zxg##NXT##B = MFMA16(xa_##NXT##1, bD1, zxg##NXT##B);                        \
    /* chain links 2..4 of step TT (link 1 done pre-barrier last step) */       \
    f32x4 fa = MFMA16(ca1, bRA1, l1fa);                                         \
    f32x4 fb = MFMA16(ca1, bRB1, l1fb);                                         \
    f32x4 ga = MFMA16(ca1, bRC1, l1ga);                                         \
    f32x4 gb = MFMA16(ca1, bRD1, l1gb);                                         \
    fa = MFMA16(ca2, bRA2, fa); fb = MFMA16(ca2, bRB2, fb);                     \
    ga = MFMA16(ca2, bRC2, ga); gb = MFMA16(ca2, bRD2, gb);                     \
    fa = MFMA16(ca3, bRA3, fa); fb = MFMA16(ca3, bRB3, fb);                     \
    ga = MFMA16(ca3, bRC3, ga); gb = MFMA16(ca3, bRD3, gb);                     \
    /* convert x(TT+2); refill raw regs with x(TT+4) */                         \
    CVT8(xa_##CUR##0, xa_##CUR##1, xr_##CUR##0, xr_##CUR##1, xr_##CUR##2, xr_##CUR##3) \
    {                                                                           \
      const int tn = ((TT) + 4) & (T - 1);                                      \
      const float* xp = xbase + (size_t)tn * IN;                                \
      xr_##CUR##0 = *(const f4*)(xp);                                           \
      xr_##CUR##1 = *(const f4*)(xp + 4);                                       \
      xr_##CUR##2 = *(const f4*)(xp + 32);                                      \
      xr_##CUR##3 = *(const f4*)(xp + 36);                                      \
    }                                                                           \
    /* gates -> c(TT+1) into cbuf[P^1] */                                       \
    char* cn_ = cbuf[(P) ^ 1];                                                  \
    GATEPK(0) GATEPK(1) GATEPK(2) GATEPK(3)                                     \
    /* own fragment of c(TT+1): wave-local, no barrier needed (in-order LDS) */ \
    h16x8 caO = *(const h16x8*)((const char*)cbuf[(P) ^ 1] + ro0);              \
    l1fa = MFMA16(caO, bRA0, zxf##NXT##A);                                      \
    l1fb = MFMA16(caO, bRB0, zxf##NXT##B);                                      \
    l1ga = MFMA16(caO, bRC0, zxg##NXT##A);                                      \
    l1gb = MFMA16(caO, bRD0, zxg##NXT##B);                                      \
    /* LDS-only barrier: publish writes; global prefetch stays in flight */     \
    asm volatile("s_waitcnt lgkmcnt(0)\n\ts_barrier" ::: "memory");             \
  }

__global__ __launch_bounds__(256, 1)
void llrnn_f16(const float* __restrict__ in,   // [B,T,IN]
               const float* __restrict__ Km,   // [IN,ZDIM]
               const float* __restrict__ Rm,   // [CELL,ZDIM]
               const float* __restrict__ bz,   // [ZDIM]
               const float* __restrict__ Wd,   // [CELL,OUTD]
               const float* __restrict__ bd,   // [OUTD]
               float* __restrict__ out)        // [B,OUTD]
{
  // c state as fp16 [16 rows][128 cells], chunk-XOR-swizzled, double-buffered.
  // byte(r,j) = r*256 + 16*((j>>3)^(r&7)) + (2j&15)
  __shared__ __align__(16) char cbuf[2][M * CELL * 2];   // 2 x 4 KB
  __shared__ float cfin[M * CELL];

  const int tid = threadIdx.x;
  const int w = tid >> 6;        // wave 0..3
  const int l = tid & 63;
  const int q = l & 15;          // A-row / D-col within tile
  const int g = l >> 4;          // k-group 0..3
  const int rb = blockIdx.x * M;
  const int colA = 32 * w + 2 * q;    // even cell column owned by this lane
  const int colB = colA + 1;          // odd cell column

  // zero c(t=0) buffer (4 KB)
  {
    u32t* z0 = (u32t*)cbuf[0];
    z0[tid] = 0; z0[tid + 256] = 0; z0[tid + 512] = 0; z0[tid + 768] = 0;
  }

  const float SF = -1.44269504f;  // -log2(e): fold into f-gate weights
  const float SG =  2.88539008f;  //  2*log2(e): fold into g-gate weights

  // fragment rotation: own fragment = w; link j reads fragment (w+j)&3
  const int f1 = (w + 1) & 3, f2 = (w + 2) & 3, f3 = (w + 3) & 3;

  // ---- preload scaled weight columns as fp16 frags, pinned in VGPRs ----
  // x-part: bA0,bA1 (f even), bB (f odd), bC (g even), bD (g odd)
  // c-part rotated: bR{A,B,C,D}{j} = R k-fragment (w+j)&3
  h16x8 bA0,bA1, bB0,bB1, bC0,bC1, bD0,bD1;
  h16x8 bRA0,bRA1,bRA2,bRA3, bRB0,bRB1,bRB2,bRB3,
        bRC0,bRC1,bRC2,bRC3, bRD0,bRD1,bRD2,bRD3;
#define LOADK(DST, COL, KT, SC)                                                 \
  {                                                                             \
    _Pragma("unroll") for (int e = 0; e < 8; ++e) {                             \
      const int krow = 32 * (KT) + 8 * g + e;                                   \
      DST[e] = (_Float16)(Km[(size_t)krow * ZDIM + (COL)] * (SC));              \
    }                                                                           \
  }
#define LOADR(DST, COL, FJ, SC)                                                 \
  {                                                                             \
    _Pragma("unroll") for (int e = 0; e < 8; ++e) {                             \
      const int krow = 32 * (FJ) + 8 * g + e;                                   \
      DST[e] = (_Float16)(Rm[(size_t)krow * ZDIM + (COL)] * (SC));              \
    }                                                                           \
  }
  LOADK(bA0,colA,0,SF) LOADK(bA1,colA,1,SF)
  LOADK(bB0,colB,0,SF) LOADK(bB1,colB,1,SF)
  LOADK(bC0,colA+CELL,0,SG) LOADK(bC1,colA+CELL,1,SG)
  LOADK(bD0,colB+CELL,0,SG) LOADK(bD1,colB+CELL,1,SG)
  LOADR(bRA0,colA,w,SF)  LOADR(bRA1,colA,f1,SF)  LOADR(bRA2,colA,f2,SF)  LOADR(bRA3,colA,f3,SF)
  LOADR(bRB0,colB,w,SF)  LOADR(bRB1,colB,f1,SF)  LOADR(bRB2,colB,f2,SF)  LOADR(bRB3,colB,f3,SF)
  LOADR(bRC0,colA+CELL,w,SG)  LOADR(bRC1,colA+CELL,f1,SG)  LOADR(bRC2,colA+CELL,f2,SG)  LOADR(bRC3,colA+CELL,f3,SG)
  LOADR(bRD0,colB+CELL,w,SG)  LOADR(bRD1,colB+CELL,f1,SG)  LOADR(bRD2,colB+CELL,f2,SG)  LOADR(bRD3,colB+CELL,f3,SG)
#undef LOADK
#undef LOADR
  // pin weight frags in arch VGPRs (R8-proven; "+a" regressed in R9)
  asm volatile("" : "+v"(bA0),"+v"(bA1),"+v"(bB0),"+v"(bB1),
                    "+v"(bC0),"+v"(bC1),"+v"(bD0),"+v"(bD1));
  asm volatile("" : "+v"(bRA0),"+v"(bRA1),"+v"(bRA2),"+v"(bRA3),
                    "+v"(bRB0),"+v"(bRB1),"+v"(bRB2),"+v"(bRB3),
                    "+v"(bRC0),"+v"(bRC1),"+v"(bRC2),"+v"(bRC3),
                    "+v"(bRD0),"+v"(bRD1),"+v"(bRD2),"+v"(bRD3));

  const float bA_ = bz[colA] * SF, bB_ = bz[colB] * SF;
  const float bC_ = bz[colA + CELL] * SG, bD_ = bz[colB + CELL] * SG;
  f32x4 bqA = {bA_, bA_, bA_, bA_};
  f32x4 bqB = {bB_, bB_, bB_, bB_};
  f32x4 bqC = {bC_, bC_, bC_, bC_};
  f32x4 bqD = {bD_, bD_, bD_, bD_};
  asm volatile("" : "+v"(bqA), "+v"(bqB), "+v"(bqC), "+v"(bqD));

  // LDS byte offsets: read frag j at rotated index, writes at own cells
  const int ro0 = q * 256 + 16 * ((4 * w  + g) ^ (q & 7));
  const int ro1 = q * 256 + 16 * ((4 * f1 + g) ^ (q & 7));
  const int ro2 = q * 256 + 16 * ((4 * f2 + g) ^ (q & 7));
  const int ro3 = q * 256 + 16 * ((4 * f3 + g) ^ (q & 7));
  int woPk[4];
#pragma unroll
  for (int i = 0; i < 4; ++i) {
    const int r = 4 * g + i;
    woPk[i] = r * 256 + 16 * ((4 * w + (q >> 2)) ^ (r & 7)) + ((4 * q) & 15);
  }

  // per-lane x base (row rb+q, k-offset 8g); step offset is uniform
  const float* xbase = in + (size_t)(rb + q) * T * IN + 8 * g;

  // ---- prologue ----
  f4 xr_E0 = *(const f4*)(xbase);
  f4 xr_E1 = *(const f4*)(xbase + 4);
  f4 xr_E2 = *(const f4*)(xbase + 32);
  f4 xr_E3 = *(const f4*)(xbase + 36);
  f4 xr_O0 = *(const f4*)(xbase + IN);
  f4 xr_O1 = *(const f4*)(xbase + IN + 4);
  f4 xr_O2 = *(const f4*)(xbase + IN + 32);
  f4 xr_O3 = *(const f4*)(xbase + IN + 36);

  h16x8 xa_E0, xa_E1, xa_O0, xa_O1;
  CVT8(xa_E0, xa_E1, xr_E0, xr_E1, xr_E2, xr_E3)   // x(0)
  CVT8(xa_O0, xa_O1, xr_O0, xr_O1, xr_O2, xr_O3)   // x(1)

  f32x4 zxfEA, zxfEB, zxgEA, zxgEB, zxfOA, zxfOB, zxgOA, zxgOB;
  // zx(0) = bias + x(0)@K
  zxfEA = MFMA16(xa_E0, bA0, bqA);
  zxfEB = MFMA16(xa_E0, bB0, bqB);
  zxgEA = MFMA16(xa_E0, bC0, bqC);
  zxgEB = MFMA16(xa_E0, bD0, bqD);
  zxfEA = MFMA16(xa_E1, bA1, zxfEA);
  zxfEB = MFMA16(xa_E1, bB1, zxfEB);
  zxgEA = MFMA16(xa_E1, bC1, zxgEA);
  zxgEB = MFMA16(xa_E1, bD1, zxgEB);

  // refill raw regs: xr_E <- x(2), xr_O <- x(3)
  xr_E0 = *(const f4*)(xbase + 2 * IN);
  xr_E1 = *(const f4*)(xbase + 2 * IN + 4);
  xr_E2 = *(const f4*)(xbase + 2 * IN + 32);
  xr_E3 = *(const f4*)(xbase + 2 * IN + 36);
  xr_O0 = *(const f4*)(xbase + 3 * IN);
  xr_O1 = *(const f4*)(xbase + 3 * IN + 4);
  xr_O2 = *(const f4*)(xbase + 3 * IN + 32);
  xr_O3 = *(const f4*)(xbase + 3 * IN + 36);

  f32x4 cregA = {0.f, 0.f, 0.f, 0.f};   // fp32 master state, col colA
  f32x4 cregB = {0.f, 0.f, 0.f, 0.f};   // fp32 master state, col colB

  __syncthreads();   // c(0) zeros visible to all waves

  // link 1 of step 0: own fragment of c(0) (zeros), seeded with zx(0)
  f32x4 l1fa, l1fb, l1ga, l1gb;
  {
    h16x8 caO = *(const h16x8*)((const char*)cbuf[0] + ro0);
    l1fa = MFMA16(caO, bRA0, zxfEA);
    l1fb = MFMA16(caO, bRB0, zxfEB);
    l1ga = MFMA16(caO, bRC0, zxgEA);
    l1gb = MFMA16(caO, bRD0, zxgEB);
  }

  for (int t = 0; t < T; t += 2) {
    STEP(E, O, t, 0)       // consumes l1(zxE), produces zxO + l1 for t+1
    STEP(O, E, t + 1, 1)   // consumes l1(zxO), produces zxE + l1 for t+2
  }

  // ---- final c (fp32) to LDS, dense epilogue out = h @ Wd + bd ----
#pragma unroll
  for (int i = 0; i < 4; ++i) {
    cfin[(4 * g + i) * CELL + colA] = cregA[i];
    cfin[(4 * g + i) * CELL + colB] = cregB[i];
  }
  __syncthreads();

  const int o = tid & 63;
  const int rp = tid >> 6;   // 0..3: rows rp, rp+4, rp+8, rp+12
  float a0 = bd[o], a1 = bd[o], a2 = bd[o], a3 = bd[o];
#pragma unroll 4
  for (int k = 0; k < CELL; ++k) {
    const float wv = Wd[(size_t)k * OUTD + o];
    a0 += cfin[rp * CELL + k] * wv;
    a1 += cfin[(rp + 4) * CELL + k] * wv;
    a2 += cfin[(rp + 8) * CELL + k] * wv;
    a3 += cfin[(rp + 12) * CELL + k] * wv;
  }
  out[(size_t)(rb + rp) * OUTD + o] = a0;
  out[(size_t)(rb + rp + 4) * OUTD + o] = a1;
  out[(size_t)(rb + rp + 8) * OUTD + o] = a2;
  out[(size_t)(rb + rp + 12) * OUTD + o] = a3;
}

extern "C" void kernel_launch(void* const* d_in, const int* in_sizes, int n_in,
                              void* d_out, int out_size, void* d_ws, size_t ws_size,
                              hipStream_t stream) {
  const float* in  = (const float*)d_in[0];
  const float* Km  = (const float*)d_in[1];
  const float* Rm  = (const float*)d_in[2];
  const float* bz  = (const float*)d_in[3];
  const float* Wd  = (const float*)d_in[4];
  const float* bd  = (const float*)d_in[5];
  float* out = (float*)d_out;

  dim3 grid(BATCH / M);   // 256 blocks -> 1 per CU
  dim3 block(256);        // 4 waves -> 1 per SIMD
  hipLaunchKernelGGL(llrnn_f16, grid, block, 0, stream,
                     in, Km, Rm, bz, Wd, bd, out);
}